// Round 17
// baseline (93.294 us; speedup 1.0000x reference)
//
#include <hip/hip_runtime.h>

#define BATCH 2
#define C 512
#define C2 256
#define V 4096          // 16*16*16
#define NROWS 8192      // BATCH*V
#define EPS 1e-5f
#define SLOPE 0.01f
#define BPAD 40         // padded LDS row stride (edge-B only)

typedef __bf16 bf16;
typedef __bf16 bf16x8 __attribute__((ext_vector_type(8)));
typedef __bf16 bf16x4 __attribute__((ext_vector_type(4)));
typedef float  f32x4  __attribute__((ext_vector_type(4)));

__device__ __forceinline__ float leaky(float x) { return x >= 0.f ? x : SLOPE * x; }

__device__ __forceinline__ int nbr(int v, int k) {
    int h = v & 15, w = (v >> 4) & 15, d = v >> 8;
    switch (k) {
        case 0: return (v & 0x0FF) | (((d + 15) & 15) << 8);
        case 1: return (v & 0x0FF) | (((d + 1) & 15) << 8);
        case 2: return (v & 0xF0F) | (((w + 15) & 15) << 4);
        case 3: return (v & 0xF0F) | (((w + 1) & 15) << 4);
        case 4: return (v & 0xFF0) | ((h + 15) & 15);
        default: return (v & 0xFF0) | ((h + 1) & 15);
    }
}

// async 16B global->LDS
__device__ __forceinline__ void gload16(const bf16* g, bf16* l) {
    __builtin_amdgcn_global_load_lds(
        (const __attribute__((address_space(1))) void*)g,
        (__attribute__((address_space(3))) void*)l, 16, 0, 0);
}

// A tile 128x32, 8 waves: wave wv covers rows wv*16..+16 (1 call)
__device__ __forceinline__ void stageA8(bf16* buf, const bf16* src, size_t ld,
                                        int kcol, int wv, int lane) {
    const int rl = wv * 16;
    gload16(src + (size_t)(rl + (lane >> 2)) * ld + kcol + (lane & 3) * 8,
            buf + rl * 32);
}
// B tile 256x32, 8 waves: wave wv covers rows wv*32..+32 (2 calls)
__device__ __forceinline__ void stageB8(bf16* buf, const bf16* src, size_t ld,
                                        int kcol, int wv, int lane) {
    #pragma unroll
    for (int j = 0; j < 2; j++) {
        const int rl = wv * 32 + j * 16;
        gload16(src + (size_t)(rl + (lane >> 2)) * ld + kcol + (lane & 3) * 8,
                buf + rl * 32);
    }
}

// wave step: BK=32, wave tile 64x64, 8 ds_read_b128, 16 MFMA
template<int SA, int SB>
__device__ __forceinline__ void mm32(const bf16* A, const bf16* B,
                                     f32x4 (&acc)[4][4], int abase, int bbase,
                                     int lr, int kg)
{
    bf16x8 af[4], bv[4];
    #pragma unroll
    for (int mb = 0; mb < 4; mb++)
        af[mb] = *(const bf16x8*)(A + (abase + mb * 16 + lr) * SA + kg * 8);
    #pragma unroll
    for (int nb = 0; nb < 4; nb++)
        bv[nb] = *(const bf16x8*)(B + (bbase + nb * 16 + lr) * SB + kg * 8);
    #pragma unroll
    for (int mb = 0; mb < 4; mb++)
        #pragma unroll
        for (int nb = 0; nb < 4; nb++)
            acc[mb][nb] = __builtin_amdgcn_mfma_f32_16x16x32_bf16(af[mb], bv[nb], acc[mb][nb], 0, 0, 0);
}

// round-10 k_out staging/step: 128x64, XOR source-swizzle, BK=64
__device__ __forceinline__ void stage_gl64(bf16* buf, const bf16* srcbase, size_t ld,
                                           int kcol, int wv, int lane) {
    const int sslot = ((lane & 7) ^ (lane >> 3)) * 8;
    #pragma unroll
    for (int j = 0; j < 4; j++) {
        const int rl = wv * 32 + j * 8;
        gload16(srcbase + (size_t)(rl + (lane >> 3)) * ld + kcol + sslot,
                buf + rl * 64);
    }
}
__device__ __forceinline__ void mmstep64(const bf16* A, const bf16* B,
                                         f32x4 (&acc)[4][4], int abase, int bbase,
                                         int lr, int kg)
{
    #pragma unroll
    for (int sub = 0; sub < 2; sub++) {
        const int slot = ((sub * 4 + kg) ^ (lr & 7)) * 8;
        bf16x8 af[4], bv[4];
        #pragma unroll
        for (int mb = 0; mb < 4; mb++)
            af[mb] = *(const bf16x8*)(A + (abase + mb * 16 + lr) * 64 + slot);
        #pragma unroll
        for (int nb = 0; nb < 4; nb++)
            bv[nb] = *(const bf16x8*)(B + (bbase + nb * 16 + lr) * 64 + slot);
        #pragma unroll
        for (int mb = 0; mb < 4; mb++)
            #pragma unroll
            for (int nb = 0; nb < 4; nb++)
                acc[mb][nb] = __builtin_amdgcn_mfma_f32_16x16x32_bf16(af[mb], bv[nb], acc[mb][nb], 0, 0, 0);
    }
}

// ---------------------------------------------------------------------------
// k_pa: merged prep (blocks 0..4095) + aggT (blocks 4096..5119).
// ---------------------------------------------------------------------------
__global__ __launch_bounds__(256) void k_pa(
    const float* __restrict__ x, const float* __restrict__ topo,
    const float* wv, const float* we, const float* wf,
    const float* w_ea, const float* b_ea, const float* g_ea, const float* be_ea,
    const float* rm_ea, const float* rv_ea,
    const float* b_v, const float* g_v, const float* be_v, const float* rm_v, const float* rv_v,
    const float* b_e, const float* g_e, const float* be_e, const float* rm_e, const float* rv_e,
    const float* w_r, const float* b_r, const float* g_r, const float* be_r,
    const float* rm_r, const float* rv_r,
    const float* g_f, const float* be_f, const float* rm_f, const float* rv_f,
    float* P, float* obv, float* obe, float* obf,
    bf16* wmain, bf16* we2, bf16* owf,
    bf16* __restrict__ xT, bf16* __restrict__ aggT)
{
    __shared__ float T[64][65];
    if (blockIdx.x < 4096) {
        int i = blockIdx.x * 256 + threadIdx.x;
        if (i < 524288) {
            int o = i >> 10, c = i & 1023;
            float val;
            if (o < 256) val = rsqrtf(rv_v[o] + EPS) * g_v[o] * wv[(size_t)o * 1024 + c];
            else {
                int oe = o - 256;
                val = (c < 512) ? rsqrtf(rv_e[oe] + EPS) * g_e[oe] * we[(size_t)oe * 1024 + c] : 0.f;
            }
            wmain[i] = (bf16)val;
        } else if (i < 655360) {
            int j = i - 524288; int o = j >> 9, c = j & 511;
            we2[j] = (bf16)(rsqrtf(rv_e[o] + EPS) * g_e[o] * we[(size_t)o * 1024 + 512 + c]);
        } else if (i < 1048576) {
            int j = i - 655360; int o = j / 768;
            owf[j] = (bf16)(rsqrtf(rv_f[o] + EPS) * g_f[o] * wf[j]);
        }
        if (blockIdx.x == 0) {
            int t = threadIdx.x;
            obf[t]       = be_f[t]       - rsqrtf(rv_f[t]       + EPS) * g_f[t]       * rm_f[t];
            obf[t + 256] = be_f[t + 256] - rsqrtf(rv_f[t + 256] + EPS) * g_f[t + 256] * rm_f[t + 256];
            float sv = rsqrtf(rv_v[t] + EPS) * g_v[t];
            obv[t] = sv * (b_v[t] - rm_v[t]) + be_v[t];
            float se = rsqrtf(rv_e[t] + EPS) * g_e[t];
            obe[t] = se * (b_e[t] - rm_e[t]) + be_e[t];
            if (t < 6) {
                float sa = rsqrtf(rv_ea[0] + EPS) * g_ea[0];
                P[t] = sa * w_ea[t];
                float sr = rsqrtf(rv_r[0] + EPS) * g_r[0];
                P[8 + t] = sr * w_r[t];
            }
            if (t == 6) {
                float sa = rsqrtf(rv_ea[0] + EPS) * g_ea[0];
                P[6] = sa * (b_ea[0] - rm_ea[0]) + be_ea[0];
                float sr = rsqrtf(rv_r[0] + EPS) * g_r[0];
                P[14] = sr * (b_r[0] - rm_r[0]) + be_r[0];
            }
        }
        return;
    }
    const int idx = blockIdx.x - 4096;
    const int vt = (idx & 63) * 64;
    const int ct = ((idx >> 6) & 7) * 64;
    const int b  = idx >> 9;
    const int t = threadIdx.x;
    const int cl = t >> 2;
    const int c  = ct + cl;
    const int vl0 = (t & 3) * 16;
    const int v0 = vt + vl0;
    const int w = (v0 >> 4) & 15, d = v0 >> 8;
    const float* xp = x + (((size_t)b * C + c) << 12);

    float xr[16], xd0[16], xd1[16], xw0[16], xw1[16];
    #pragma unroll
    for (int i = 0; i < 4; i++) {
        float4 a;
        a = ((const float4*)(xp + v0))[i];                        xr [4*i]=a.x; xr [4*i+1]=a.y; xr [4*i+2]=a.z; xr [4*i+3]=a.w;
        a = ((const float4*)(xp + (((d+15)&15)<<8) + (w<<4)))[i]; xd0[4*i]=a.x; xd0[4*i+1]=a.y; xd0[4*i+2]=a.z; xd0[4*i+3]=a.w;
        a = ((const float4*)(xp + (((d+ 1)&15)<<8) + (w<<4)))[i]; xd1[4*i]=a.x; xd1[4*i+1]=a.y; xd1[4*i+2]=a.z; xd1[4*i+3]=a.w;
        a = ((const float4*)(xp + (d<<8) + (((w+15)&15)<<4)))[i]; xw0[4*i]=a.x; xw0[4*i+1]=a.y; xw0[4*i+2]=a.z; xw0[4*i+3]=a.w;
        a = ((const float4*)(xp + (d<<8) + (((w+ 1)&15)<<4)))[i]; xw1[4*i]=a.x; xw1[4*i+1]=a.y; xw1[4*i+2]=a.z; xw1[4*i+3]=a.w;
    }

    #pragma unroll
    for (int p = 0; p < 2; ++p) {
        float val[16];
        if (p == 0) {
            #pragma unroll
            for (int j = 0; j < 16; j++) val[j] = xr[j];
        } else {
            #pragma unroll
            for (int j = 0; j < 16; j++) {
                const float* tp = topo + (size_t)(v0 + j) * 6;
                float s = P[6];
                s = fmaf(P[0], fmaf(xd0[j], xr[j], tp[0]), s);
                s = fmaf(P[1], fmaf(xd1[j], xr[j], tp[1]), s);
                s = fmaf(P[2], fmaf(xw0[j], xr[j], tp[2]), s);
                s = fmaf(P[3], fmaf(xw1[j], xr[j], tp[3]), s);
                s = fmaf(P[4], fmaf(xr[(j+15)&15], xr[j], tp[4]), s);
                s = fmaf(P[5], fmaf(xr[(j+ 1)&15], xr[j], tp[5]), s);
                val[j] = leaky(s);
            }
        }
        __syncthreads();
        #pragma unroll
        for (int j = 0; j < 16; j++) T[cl][vl0 + j] = val[j];
        __syncthreads();
        const int vr = t >> 2, c0 = (t & 3) * 16;
        bf16x8 lo, hi;
        #pragma unroll
        for (int i = 0; i < 8; i++) {
            lo[i] = (bf16)T[c0 + i][vr];
            hi[i] = (bf16)T[c0 + 8 + i][vr];
        }
        bf16* dst = (p == 0) ? xT : aggT;
        bf16* dp = dst + ((size_t)(b << 12) + vt + vr) * C + ct + c0;
        *(bf16x8*)dp = lo;
        *(bf16x8*)(dp + 8) = hi;
    }
}

// ---------------------------------------------------------------------------
// k_gemm: BM=128, BN=256, BK=32, 512 thr (8 waves 2m x 4n), wave tile 64x64.
// A+B via gload_lds linear (MAIN); edge-B reg-staged into padded LDS.
// One __syncthreads per step (round-8 ordering). LDS 56KB -> 2 blocks/CU.
// ---------------------------------------------------------------------------
template<bool MAIN>
__device__ __forceinline__ void gemm_body(
    int m0, int n0, int kk, int nsteps,
    const bf16* __restrict__ wA, size_t ldA,
    const bf16* __restrict__ xT, const bf16* __restrict__ aggT,
    const float* __restrict__ topo, const float* __restrict__ bvp,
    bf16* __restrict__ uvT, float* __restrict__ sxe, bf16* __restrict__ se,
    bf16 (*A)[128 * 32], bf16 (*B)[256 * BPAD])
{
    const int t = threadIdx.x, lane = t & 63;
    const int wv = t >> 6, wmi = wv >> 2, wni = wv & 3;
    const int lr = lane & 15, kg = lane >> 4;

    const bf16* wAb  = wA + (size_t)m0 * ldA;
    const bf16* xTb  = xT + (size_t)n0 * C;
    const bf16* agTb = aggT + (size_t)n0 * C;

    const int erow = t >> 1, ecol = (t & 1) * 16;
    const bf16* pBx = nullptr; const bf16* pB2 = nullptr; float tp = 0.f;
    if (!MAIN) {
        const int rB = n0 + erow;
        const int vvv = rB & 4095, bb = rB >> 12;
        pBx = xT + (size_t)rB * C + ecol;
        pB2 = xT + (size_t)((bb << 12) | nbr(vvv, kk)) * C + ecol;
        tp = topo[vvv * 6 + kk];
    }

    f32x4 acc[4][4];
    #pragma unroll
    for (int mb = 0; mb < 4; mb++)
        #pragma unroll
        for (int nb = 0; nb < 4; nb++) acc[mb][nb] = 0.f;

    uint4 b0, b1, n0r, n1r;
    auto issueB = [&](int s) {
        b0  = *(const uint4*)(pBx + s * 32);
        b1  = *(const uint4*)(pBx + s * 32 + 8);
        n0r = *(const uint4*)(pB2 + s * 32);
        n1r = *(const uint4*)(pB2 + s * 32 + 8);
    };
    auto commitB = [&](int buf) {
        bf16x8 xa0 = *(bf16x8*)&b0, xn0 = *(bf16x8*)&n0r;
        bf16x8 xa1 = *(bf16x8*)&b1, xn1 = *(bf16x8*)&n1r;
        bf16x8 e0, e1;
        #pragma unroll
        for (int i = 0; i < 8; i++) {
            e0[i] = (bf16)fmaf((float)xa0[i], (float)xn0[i], tp);
            e1[i] = (bf16)fmaf((float)xa1[i], (float)xn1[i], tp);
        }
        *(bf16x8*)(&B[buf][erow * BPAD + ecol])     = e0;
        *(bf16x8*)(&B[buf][erow * BPAD + ecol + 8]) = e1;
    };
    auto stageStep = [&](int buf, int s) {
        stageA8(A[buf], wAb, ldA, s * 32, wv, lane);
        if (MAIN) {
            if (s < 16) stageB8((bf16*)B[buf], xTb, C, s * 32, wv, lane);
            else        stageB8((bf16*)B[buf], agTb, C, (s - 16) * 32, wv, lane);
        }
    };

    stageStep(0, 0);
    if (!MAIN) { issueB(0); commitB(0); if (nsteps > 1) issueB(1); }

    int cb = 0;
    #pragma unroll 1
    for (int s = 0; s < nsteps; ++s) {
        __syncthreads();
        if (s + 1 < nsteps) stageStep(cb ^ 1, s + 1);
        if (MAIN) mm32<32, 32>(A[cb], (const bf16*)B[cb], acc, wmi * 64, wni * 64, lr, kg);
        else      mm32<32, BPAD>(A[cb], (const bf16*)B[cb], acc, wmi * 64, wni * 64, lr, kg);
        if (!MAIN && s + 1 < nsteps) {
            commitB(cb ^ 1);
            if (s + 2 < nsteps) issueB(s + 2);
        }
        cb ^= 1;
    }

    if (MAIN) {
        if (m0 < 256) {
            #pragma unroll
            for (int mb = 0; mb < 4; mb++) {
                const int o = m0 + wmi * 64 + mb * 16 + kg * 4;
                f32x4 bv4 = *(const f32x4*)(bvp + o);
                #pragma unroll
                for (int nb = 0; nb < 4; nb++) {
                    const int col = n0 + wni * 64 + nb * 16 + lr;
                    bf16x4 o4;
                    #pragma unroll
                    for (int q = 0; q < 4; q++)
                        o4[q] = (bf16)leaky(acc[mb][nb][q] + bv4[q]);
                    *(bf16x4*)(uvT + (size_t)col * C2 + o) = o4;
                }
            }
        } else {
            #pragma unroll
            for (int mb = 0; mb < 4; mb++) {
                const int o = (m0 - 256) + wmi * 64 + mb * 16 + kg * 4;
                #pragma unroll
                for (int nb = 0; nb < 4; nb++) {
                    const int col = n0 + wni * 64 + nb * 16 + lr;
                    *(f32x4*)(sxe + (size_t)col * C2 + o) = acc[mb][nb];
                }
            }
        }
    } else {
        #pragma unroll
        for (int mb = 0; mb < 4; mb++) {
            const int o = m0 + wmi * 64 + mb * 16 + kg * 4;
            #pragma unroll
            for (int nb = 0; nb < 4; nb++) {
                const int col = n0 + wni * 64 + nb * 16 + lr;
                bf16x4 o4;
                #pragma unroll
                for (int q = 0; q < 4; q++) o4[q] = (bf16)acc[mb][nb][q];
                *(bf16x4*)(se + ((size_t)kk * NROWS + col) * C2 + o) = o4;
            }
        }
    }
}

// 512 blocks: 128 main (4 m-tiles x 32 n-panels) + 384 edge (2m x 6kk x 32n).
__global__ __launch_bounds__(512, 2) void k_gemm(
    const bf16* __restrict__ xT, const bf16* __restrict__ aggT,
    const bf16* __restrict__ wm, const bf16* __restrict__ we2,
    const float* __restrict__ bvp, const float* __restrict__ topo,
    bf16* __restrict__ uvT, float* __restrict__ sxe, bf16* __restrict__ se)
{
    __shared__ __align__(16) bf16 A[2][128 * 32];
    __shared__ __align__(16) bf16 B[2][256 * BPAD];
    const int bid = blockIdx.x;
    if (bid < 128) {
        const int m0 = (bid & 3) * 128, n0 = (bid >> 2) * 256;
        const int nsteps = (m0 < 256) ? 32 : 16;
        gemm_body<true>(m0, n0, 0, nsteps, wm, 1024, xT, aggT, topo, bvp,
                        uvT, sxe, nullptr, A, B);
    } else {
        const int e = bid - 128;
        const int m0 = (e & 1) * 128;
        const int g = e >> 1, kk = g % 6, n0 = (g / 6) * 256;
        gemm_body<false>(m0, n0, kk, 16, we2, 512, xT, aggT, topo, bvp,
                         nullptr, nullptr, se, A, B);
    }
}

// ---------------------------------------------------------------------------
// k_comb: ur = sum_k wr'_k * leaky(sxe + se_k + be'); updT = uvT * leaky(ur+br')
// ---------------------------------------------------------------------------
__global__ __launch_bounds__(256) void k_comb(
    const float* __restrict__ sxe, const bf16* __restrict__ se,
    const bf16* __restrict__ uvT, const float* __restrict__ bep,
    const float* __restrict__ P, bf16* __restrict__ updT)
{
    const int g = blockIdx.x * 256 + threadIdx.x;
    const int row = g >> 5, o0 = (g & 31) * 8;
    const size_t base = (size_t)row * C2 + o0;

    f32x4 sx0 = *(const f32x4*)(sxe + base);
    f32x4 sx1 = *(const f32x4*)(sxe + base + 4);
    f32x4 be0 = *(const f32x4*)(bep + o0);
    f32x4 be1 = *(const f32x4*)(bep + o0 + 4);
    float ur[8] = {};
    #pragma unroll
    for (int k = 0; k < 6; k++) {
        bf16x8 s8 = *(const bf16x8*)(se + (size_t)k * NROWS * C2 + base);
        const float wrk = P[8 + k];
        #pragma unroll
        for (int i = 0; i < 4; i++) {
            ur[i]     = fmaf(wrk, leaky(sx0[i] + (float)s8[i]     + be0[i]), ur[i]);
            ur[i + 4] = fmaf(wrk, leaky(sx1[i] + (float)s8[i + 4] + be1[i]), ur[i + 4]);
        }
    }
    const float brp = P[14];
    bf16x8 uv8 = *(const bf16x8*)(uvT + base);
    bf16x8 o8;
    #pragma unroll
    for (int i = 0; i < 8; i++)
        o8[i] = (bf16)((float)uv8[i] * leaky(ur[i] + brp));
    *(bf16x8*)(updT + base) = o8;
}

// ---------------------------------------------------------------------------
// k_out: round-10/16 version (BK=64, swizzled gload_lds, XCD panel swizzle).
// ---------------------------------------------------------------------------
__global__ __launch_bounds__(256, 2) void k_out(
    const bf16* __restrict__ xT, const bf16* __restrict__ updT,
    const bf16* __restrict__ wf, const float* __restrict__ bfp,
    float* __restrict__ out)
{
    __shared__ __align__(16) bf16 A[2][128 * 64];
    __shared__ __align__(16) bf16 B[2][128 * 64];
    const int t = threadIdx.x, lane = t & 63;
    const int wv = t >> 6, wmi = wv >> 1, wni = wv & 1;
    const int lr = lane & 15, kg = lane >> 4;
    const int lb = (blockIdx.x & 7) * 32 + (blockIdx.x >> 3);
    const int n0 = (lb >> 2) * 128, m0 = (lb & 3) * 128;

    const bf16* wAb = wf   + (size_t)m0 * 768;
    const bf16* xTb = xT   + (size_t)n0 * C;
    const bf16* uTb = updT + (size_t)n0 * C2;

    f32x4 acc[4][4];
    #pragma unroll
    for (int mb = 0; mb < 4; mb++)
        #pragma unroll
        for (int nb = 0; nb < 4; nb++) acc[mb][nb] = 0.f;

    auto stageStep = [&](int buf, int s) {
        stage_gl64(A[buf], wAb, 768, s * 64, wv, lane);
        if (s < 8) stage_gl64(B[buf], xTb, C, s * 64, wv, lane);
        else       stage_gl64(B[buf], uTb, C2, (s - 8) * 64, wv, lane);
    };

    stageStep(0, 0);
    int cb = 0;
    #pragma unroll 1
    for (int s = 0; s < 12; ++s) {
        __syncthreads();
        if (s + 1 < 12) stageStep(cb ^ 1, s + 1);
        mmstep64(A[cb], B[cb], acc, wmi * 64, wni * 64, lr, kg);
        cb ^= 1;
    }

    #pragma unroll
    for (int mb = 0; mb < 4; mb++) {
        const int o = m0 + wmi * 64 + mb * 16 + kg * 4;
        f32x4 bf4 = *(const f32x4*)(bfp + o);
        #pragma unroll
        for (int nb = 0; nb < 4; nb++) {
            const int col = n0 + wni * 64 + nb * 16 + lr;
            const int b = col >> 12, v = col & 4095;
            #pragma unroll
            for (int q = 0; q < 4; q++)
                out[(((size_t)b * C + o + q) << 12) + v] = leaky(acc[mb][nb][q] + bf4[q]);
        }
    }
}

// ---------------------------------------------------------------------------
extern "C" void kernel_launch(void* const* d_in, const int* in_sizes, int n_in,
                              void* d_out, int out_size, void* d_ws, size_t ws_size,
                              hipStream_t stream)
{
    const float* x    = (const float*)d_in[0];
    const float* topo = (const float*)d_in[1];
    const float* w_ea = (const float*)d_in[2];
    const float* b_ea = (const float*)d_in[3];
    const float* g_ea = (const float*)d_in[4];
    const float* be_ea= (const float*)d_in[5];
    const float* rm_ea= (const float*)d_in[6];
    const float* rv_ea= (const float*)d_in[7];
    const float* w_v  = (const float*)d_in[8];
    const float* b_v  = (const float*)d_in[9];
    const float* g_v  = (const float*)d_in[10];
    const float* be_v = (const float*)d_in[11];
    const float* rm_v = (const float*)d_in[12];
    const float* rv_v = (const float*)d_in[13];
    const float* w_e  = (const float*)d_in[14];
    const float* b_e  = (const float*)d_in[15];
    const float* g_e  = (const float*)d_in[16];
    const float* be_e = (const float*)d_in[17];
    const float* rm_e = (const float*)d_in[18];
    const float* rv_e = (const float*)d_in[19];
    const float* w_r  = (const float*)d_in[20];
    const float* b_r  = (const float*)d_in[21];
    const float* g_r  = (const float*)d_in[22];
    const float* be_r = (const float*)d_in[23];
    const float* rm_r = (const float*)d_in[24];
    const float* rv_r = (const float*)d_in[25];
    const float* w_f  = (const float*)d_in[26];
    const float* g_f  = (const float*)d_in[27];
    const float* be_f = (const float*)d_in[28];
    const float* rm_f = (const float*)d_in[29];
    const float* rv_f = (const float*)d_in[30];

    char* base = (char*)d_ws;
    size_t off = 0;
    auto take = [&](size_t bytes) { size_t r = off; off = (off + bytes + 255) & ~(size_t)255; return r; };
    float* P    = (float*)(base + take(64 * 4));
    float* bvp  = (float*)(base + take(256 * 4));
    float* bep  = (float*)(base + take(256 * 4));
    float* bfp  = (float*)(base + take(512 * 4));
    bf16*  wmp  = (bf16*)(base + take((size_t)524288 * 2));
    bf16*  we2p = (bf16*)(base + take((size_t)131072 * 2));
    bf16*  wfp  = (bf16*)(base + take((size_t)393216 * 2));
    bf16*  xT   = (bf16*)(base + take((size_t)NROWS * C * 2));
    bf16*  aggT = (bf16*)(base + take((size_t)NROWS * C * 2));
    bf16*  uvT  = (bf16*)(base + take((size_t)NROWS * C2 * 2));
    bf16*  updT = (bf16*)(base + take((size_t)NROWS * C2 * 2));
    float* sxe  = (float*)(base + take((size_t)NROWS * C2 * 4));
    bf16*  se   = (bf16*)(base + take((size_t)6 * NROWS * C2 * 2));

    k_pa<<<dim3(5120), 256, 0, stream>>>(
        x, topo, w_v, w_e, w_f,
        w_ea, b_ea, g_ea, be_ea, rm_ea, rv_ea,
        b_v, g_v, be_v, rm_v, rv_v,
        b_e, g_e, be_e, rm_e, rv_e,
        w_r, b_r, g_r, be_r, rm_r, rv_r,
        g_f, be_f, rm_f, rv_f,
        P, bvp, bep, bfp, wmp, we2p, wfp, xT, aggT);

    k_gemm<<<dim3(512), 512, 0, stream>>>(xT, aggT, wmp, we2p, bvp, topo, uvT, sxe, se);
    k_comb<<<dim3(NROWS * C2 / 8 / 256), 256, 0, stream>>>(sxe, se, uvT, bep, P, updT);
    k_out<<<dim3(256), 256, 0, stream>>>(xT, updT, wfp, bfp, (float*)d_out);
}

// Round 18
// 91.373 us; speedup vs baseline: 1.0210x; 1.0210x over previous
//
#include <hip/hip_runtime.h>

#define BATCH 2
#define C 512
#define C2 256
#define V 4096          // 16*16*16
#define NROWS 8192      // BATCH*V
#define EPS 1e-5f
#define SLOPE 0.01f
#define BPAD 40         // padded LDS row stride (edge-B only)

typedef __bf16 bf16;
typedef __bf16 bf16x8 __attribute__((ext_vector_type(8)));
typedef __bf16 bf16x4 __attribute__((ext_vector_type(4)));
typedef float  f32x4  __attribute__((ext_vector_type(4)));

__device__ __forceinline__ float leaky(float x) { return x >= 0.f ? x : SLOPE * x; }

__device__ __forceinline__ int nbr(int v, int k) {
    int h = v & 15, w = (v >> 4) & 15, d = v >> 8;
    switch (k) {
        case 0: return (v & 0x0FF) | (((d + 15) & 15) << 8);
        case 1: return (v & 0x0FF) | (((d + 1) & 15) << 8);
        case 2: return (v & 0xF0F) | (((w + 15) & 15) << 4);
        case 3: return (v & 0xF0F) | (((w + 1) & 15) << 4);
        case 4: return (v & 0xFF0) | ((h + 15) & 15);
        default: return (v & 0xFF0) | ((h + 1) & 15);
    }
}

// async 16B global->LDS
__device__ __forceinline__ void gload16(const bf16* g, bf16* l) {
    __builtin_amdgcn_global_load_lds(
        (const __attribute__((address_space(1))) void*)g,
        (__attribute__((address_space(3))) void*)l, 16, 0, 0);
}

// round-8 k_gemm staging: 128x32 linear tile via gload_lds (2 calls/wave)
__device__ __forceinline__ void stage_r8(bf16* buf, const bf16* srcbase, size_t ld,
                                         int kcol, int wv, int lane) {
    #pragma unroll
    for (int j = 0; j < 2; j++) {
        const int rl = wv * 32 + j * 16;
        gload16(srcbase + (size_t)(rl + (lane >> 2)) * ld + kcol + (lane & 3) * 8,
                buf + rl * 32);
    }
}

// round-8 wave step: BK=32, wave tile 64x64, 8 ds_read_b128, 16 MFMA
template<int SA, int SB>
__device__ __forceinline__ void mm32(const bf16* A, const bf16* B,
                                     f32x4 (&acc)[4][4], int abase, int bbase,
                                     int lr, int kg)
{
    bf16x8 af[4], bv[4];
    #pragma unroll
    for (int mb = 0; mb < 4; mb++)
        af[mb] = *(const bf16x8*)(A + (abase + mb * 16 + lr) * SA + kg * 8);
    #pragma unroll
    for (int nb = 0; nb < 4; nb++)
        bv[nb] = *(const bf16x8*)(B + (bbase + nb * 16 + lr) * SB + kg * 8);
    #pragma unroll
    for (int mb = 0; mb < 4; mb++)
        #pragma unroll
        for (int nb = 0; nb < 4; nb++)
            acc[mb][nb] = __builtin_amdgcn_mfma_f32_16x16x32_bf16(af[mb], bv[nb], acc[mb][nb], 0, 0, 0);
}

// round-10 k_out staging/step: 128x64, XOR source-swizzle, BK=64
__device__ __forceinline__ void stage_gl64(bf16* buf, const bf16* srcbase, size_t ld,
                                           int kcol, int wv, int lane) {
    const int sslot = ((lane & 7) ^ (lane >> 3)) * 8;
    #pragma unroll
    for (int j = 0; j < 4; j++) {
        const int rl = wv * 32 + j * 8;
        gload16(srcbase + (size_t)(rl + (lane >> 3)) * ld + kcol + sslot,
                buf + rl * 64);
    }
}
__device__ __forceinline__ void mmstep64(const bf16* A, const bf16* B,
                                         f32x4 (&acc)[4][4], int abase, int bbase,
                                         int lr, int kg)
{
    #pragma unroll
    for (int sub = 0; sub < 2; sub++) {
        const int slot = ((sub * 4 + kg) ^ (lr & 7)) * 8;
        bf16x8 af[4], bv[4];
        #pragma unroll
        for (int mb = 0; mb < 4; mb++)
            af[mb] = *(const bf16x8*)(A + (abase + mb * 16 + lr) * 64 + slot);
        #pragma unroll
        for (int nb = 0; nb < 4; nb++)
            bv[nb] = *(const bf16x8*)(B + (bbase + nb * 16 + lr) * 64 + slot);
        #pragma unroll
        for (int mb = 0; mb < 4; mb++)
            #pragma unroll
            for (int nb = 0; nb < 4; nb++)
                acc[mb][nb] = __builtin_amdgcn_mfma_f32_16x16x32_bf16(af[mb], bv[nb], acc[mb][nb], 0, 0, 0);
    }
}

// ---------------------------------------------------------------------------
// k_pa: merged prep (blocks 0..4095) + aggT (blocks 4096..5119).
// ---------------------------------------------------------------------------
__global__ __launch_bounds__(256) void k_pa(
    const float* __restrict__ x, const float* __restrict__ topo,
    const float* wv, const float* we, const float* wf,
    const float* w_ea, const float* b_ea, const float* g_ea, const float* be_ea,
    const float* rm_ea, const float* rv_ea,
    const float* b_v, const float* g_v, const float* be_v, const float* rm_v, const float* rv_v,
    const float* b_e, const float* g_e, const float* be_e, const float* rm_e, const float* rv_e,
    const float* w_r, const float* b_r, const float* g_r, const float* be_r,
    const float* rm_r, const float* rv_r,
    const float* g_f, const float* be_f, const float* rm_f, const float* rv_f,
    float* P, float* obv, float* obe, float* obf,
    bf16* wmain, bf16* we2, bf16* owf,
    bf16* __restrict__ xT, bf16* __restrict__ aggT)
{
    __shared__ float T[64][65];
    if (blockIdx.x < 4096) {
        int i = blockIdx.x * 256 + threadIdx.x;
        if (i < 524288) {
            int o = i >> 10, c = i & 1023;
            float val;
            if (o < 256) val = rsqrtf(rv_v[o] + EPS) * g_v[o] * wv[(size_t)o * 1024 + c];
            else {
                int oe = o - 256;
                val = (c < 512) ? rsqrtf(rv_e[oe] + EPS) * g_e[oe] * we[(size_t)oe * 1024 + c] : 0.f;
            }
            wmain[i] = (bf16)val;
        } else if (i < 655360) {
            int j = i - 524288; int o = j >> 9, c = j & 511;
            we2[j] = (bf16)(rsqrtf(rv_e[o] + EPS) * g_e[o] * we[(size_t)o * 1024 + 512 + c]);
        } else if (i < 1048576) {
            int j = i - 655360; int o = j / 768;
            owf[j] = (bf16)(rsqrtf(rv_f[o] + EPS) * g_f[o] * wf[j]);
        }
        if (blockIdx.x == 0) {
            int t = threadIdx.x;
            obf[t]       = be_f[t]       - rsqrtf(rv_f[t]       + EPS) * g_f[t]       * rm_f[t];
            obf[t + 256] = be_f[t + 256] - rsqrtf(rv_f[t + 256] + EPS) * g_f[t + 256] * rm_f[t + 256];
            float sv = rsqrtf(rv_v[t] + EPS) * g_v[t];
            obv[t] = sv * (b_v[t] - rm_v[t]) + be_v[t];
            float se = rsqrtf(rv_e[t] + EPS) * g_e[t];
            obe[t] = se * (b_e[t] - rm_e[t]) + be_e[t];
            if (t < 6) {
                float sa = rsqrtf(rv_ea[0] + EPS) * g_ea[0];
                P[t] = sa * w_ea[t];
                float sr = rsqrtf(rv_r[0] + EPS) * g_r[0];
                P[8 + t] = sr * w_r[t];
            }
            if (t == 6) {
                float sa = rsqrtf(rv_ea[0] + EPS) * g_ea[0];
                P[6] = sa * (b_ea[0] - rm_ea[0]) + be_ea[0];
                float sr = rsqrtf(rv_r[0] + EPS) * g_r[0];
                P[14] = sr * (b_r[0] - rm_r[0]) + be_r[0];
            }
        }
        return;
    }
    const int idx = blockIdx.x - 4096;
    const int vt = (idx & 63) * 64;
    const int ct = ((idx >> 6) & 7) * 64;
    const int b  = idx >> 9;
    const int t = threadIdx.x;
    const int cl = t >> 2;
    const int c  = ct + cl;
    const int vl0 = (t & 3) * 16;
    const int v0 = vt + vl0;
    const int w = (v0 >> 4) & 15, d = v0 >> 8;
    const float* xp = x + (((size_t)b * C + c) << 12);

    float xr[16], xd0[16], xd1[16], xw0[16], xw1[16];
    #pragma unroll
    for (int i = 0; i < 4; i++) {
        float4 a;
        a = ((const float4*)(xp + v0))[i];                        xr [4*i]=a.x; xr [4*i+1]=a.y; xr [4*i+2]=a.z; xr [4*i+3]=a.w;
        a = ((const float4*)(xp + (((d+15)&15)<<8) + (w<<4)))[i]; xd0[4*i]=a.x; xd0[4*i+1]=a.y; xd0[4*i+2]=a.z; xd0[4*i+3]=a.w;
        a = ((const float4*)(xp + (((d+ 1)&15)<<8) + (w<<4)))[i]; xd1[4*i]=a.x; xd1[4*i+1]=a.y; xd1[4*i+2]=a.z; xd1[4*i+3]=a.w;
        a = ((const float4*)(xp + (d<<8) + (((w+15)&15)<<4)))[i]; xw0[4*i]=a.x; xw0[4*i+1]=a.y; xw0[4*i+2]=a.z; xw0[4*i+3]=a.w;
        a = ((const float4*)(xp + (d<<8) + (((w+ 1)&15)<<4)))[i]; xw1[4*i]=a.x; xw1[4*i+1]=a.y; xw1[4*i+2]=a.z; xw1[4*i+3]=a.w;
    }

    #pragma unroll
    for (int p = 0; p < 2; ++p) {
        float val[16];
        if (p == 0) {
            #pragma unroll
            for (int j = 0; j < 16; j++) val[j] = xr[j];
        } else {
            #pragma unroll
            for (int j = 0; j < 16; j++) {
                const float* tp = topo + (size_t)(v0 + j) * 6;
                float s = P[6];
                s = fmaf(P[0], fmaf(xd0[j], xr[j], tp[0]), s);
                s = fmaf(P[1], fmaf(xd1[j], xr[j], tp[1]), s);
                s = fmaf(P[2], fmaf(xw0[j], xr[j], tp[2]), s);
                s = fmaf(P[3], fmaf(xw1[j], xr[j], tp[3]), s);
                s = fmaf(P[4], fmaf(xr[(j+15)&15], xr[j], tp[4]), s);
                s = fmaf(P[5], fmaf(xr[(j+ 1)&15], xr[j], tp[5]), s);
                val[j] = leaky(s);
            }
        }
        __syncthreads();
        #pragma unroll
        for (int j = 0; j < 16; j++) T[cl][vl0 + j] = val[j];
        __syncthreads();
        const int vr = t >> 2, c0 = (t & 3) * 16;
        bf16x8 lo, hi;
        #pragma unroll
        for (int i = 0; i < 8; i++) {
            lo[i] = (bf16)T[c0 + i][vr];
            hi[i] = (bf16)T[c0 + 8 + i][vr];
        }
        bf16* dst = (p == 0) ? xT : aggT;
        bf16* dp = dst + ((size_t)(b << 12) + vt + vr) * C + ct + c0;
        *(bf16x8*)dp = lo;
        *(bf16x8*)(dp + 8) = hi;
    }
}

// ---------------------------------------------------------------------------
// k_gemm: round-16 structure; sxe now stored as bf16 (traffic trim).
// BM=128, BN=128, BK=32, 4 waves, wave tile 64x64, identity mapping.
// ---------------------------------------------------------------------------
template<bool MAIN>
__device__ __forceinline__ void gemm_body(
    int m0, int n0, int kk, int nsteps,
    const bf16* __restrict__ wA, size_t ldA,
    const bf16* __restrict__ xT, const bf16* __restrict__ aggT,
    const float* __restrict__ topo, const float* __restrict__ bvp,
    bf16* __restrict__ uvT, bf16* __restrict__ sxe, bf16* __restrict__ se,
    bf16 (*A)[128 * 32], bf16 (*B)[128 * BPAD])
{
    const int t = threadIdx.x, lane = t & 63;
    const int wv = t >> 6, wmi = wv >> 1, wni = wv & 1;
    const int lr = lane & 15, kg = lane >> 4;

    const bf16* wAb  = wA + (size_t)m0 * ldA;
    const bf16* xTb  = xT + (size_t)n0 * C;
    const bf16* agTb = aggT + (size_t)n0 * C;

    const int erow = t >> 1, ecol = (t & 1) * 16;
    const bf16* pBx = nullptr; const bf16* pB2 = nullptr; float tp = 0.f;
    if (!MAIN) {
        const int rB = n0 + erow;
        const int vvv = rB & 4095, bb = rB >> 12;
        pBx = xT + (size_t)rB * C + ecol;
        pB2 = xT + (size_t)((bb << 12) | nbr(vvv, kk)) * C + ecol;
        tp = topo[vvv * 6 + kk];
    }

    f32x4 acc[4][4];
    #pragma unroll
    for (int mb = 0; mb < 4; mb++)
        #pragma unroll
        for (int nb = 0; nb < 4; nb++) acc[mb][nb] = 0.f;

    uint4 b0, b1, n0r, n1r;
    auto issueB = [&](int s) {
        b0  = *(const uint4*)(pBx + s * 32);
        b1  = *(const uint4*)(pBx + s * 32 + 8);
        n0r = *(const uint4*)(pB2 + s * 32);
        n1r = *(const uint4*)(pB2 + s * 32 + 8);
    };
    auto commitB = [&](int buf) {
        bf16x8 xa0 = *(bf16x8*)&b0, xn0 = *(bf16x8*)&n0r;
        bf16x8 xa1 = *(bf16x8*)&b1, xn1 = *(bf16x8*)&n1r;
        bf16x8 e0, e1;
        #pragma unroll
        for (int i = 0; i < 8; i++) {
            e0[i] = (bf16)fmaf((float)xa0[i], (float)xn0[i], tp);
            e1[i] = (bf16)fmaf((float)xa1[i], (float)xn1[i], tp);
        }
        *(bf16x8*)(&B[buf][erow * BPAD + ecol])     = e0;
        *(bf16x8*)(&B[buf][erow * BPAD + ecol + 8]) = e1;
    };
    auto stageStep = [&](int buf, int s) {
        stage_r8(A[buf], wAb, ldA, s * 32, wv, lane);
        if (MAIN) {
            if (s < 16) stage_r8((bf16*)B[buf], xTb, C, s * 32, wv, lane);
            else        stage_r8((bf16*)B[buf], agTb, C, (s - 16) * 32, wv, lane);
        }
    };

    stageStep(0, 0);
    if (!MAIN) { issueB(0); commitB(0); if (nsteps > 1) issueB(1); }

    int cb = 0;
    #pragma unroll 1
    for (int s = 0; s < nsteps; ++s) {
        __syncthreads();
        if (s + 1 < nsteps) stageStep(cb ^ 1, s + 1);
        if (MAIN) mm32<32, 32>(A[cb], (const bf16*)B[cb], acc, wmi * 64, wni * 64, lr, kg);
        else      mm32<32, BPAD>(A[cb], (const bf16*)B[cb], acc, wmi * 64, wni * 64, lr, kg);
        if (!MAIN && s + 1 < nsteps) {
            commitB(cb ^ 1);
            if (s + 2 < nsteps) issueB(s + 2);
        }
        cb ^= 1;
    }

    if (MAIN) {
        if (m0 < 256) {
            #pragma unroll
            for (int mb = 0; mb < 4; mb++) {
                const int o = m0 + wmi * 64 + mb * 16 + kg * 4;
                f32x4 bv4 = *(const f32x4*)(bvp + o);
                #pragma unroll
                for (int nb = 0; nb < 4; nb++) {
                    const int col = n0 + wni * 64 + nb * 16 + lr;
                    bf16x4 o4;
                    #pragma unroll
                    for (int q = 0; q < 4; q++)
                        o4[q] = (bf16)leaky(acc[mb][nb][q] + bv4[q]);
                    *(bf16x4*)(uvT + (size_t)col * C2 + o) = o4;
                }
            }
        } else {
            #pragma unroll
            for (int mb = 0; mb < 4; mb++) {
                const int o = (m0 - 256) + wmi * 64 + mb * 16 + kg * 4;
                #pragma unroll
                for (int nb = 0; nb < 4; nb++) {
                    const int col = n0 + wni * 64 + nb * 16 + lr;
                    bf16x4 o4;
                    #pragma unroll
                    for (int q = 0; q < 4; q++) o4[q] = (bf16)acc[mb][nb][q];
                    *(bf16x4*)(sxe + (size_t)col * C2 + o) = o4;
                }
            }
        }
    } else {
        #pragma unroll
        for (int mb = 0; mb < 4; mb++) {
            const int o = m0 + wmi * 64 + mb * 16 + kg * 4;
            #pragma unroll
            for (int nb = 0; nb < 4; nb++) {
                const int col = n0 + wni * 64 + nb * 16 + lr;
                bf16x4 o4;
                #pragma unroll
                for (int q = 0; q < 4; q++) o4[q] = (bf16)acc[mb][nb][q];
                *(bf16x4*)(se + ((size_t)kk * NROWS + col) * C2 + o) = o4;
            }
        }
    }
}

__global__ __launch_bounds__(256, 3) void k_gemm(
    const bf16* __restrict__ xT, const bf16* __restrict__ aggT,
    const bf16* __restrict__ wm, const bf16* __restrict__ we2,
    const float* __restrict__ bvp, const float* __restrict__ topo,
    bf16* __restrict__ uvT, bf16* __restrict__ sxe, bf16* __restrict__ se)
{
    __shared__ __align__(16) bf16 A[2][128 * 32];
    __shared__ __align__(16) bf16 B[2][128 * BPAD];
    const int bid = blockIdx.x;
    if (bid < 256) {
        const int m0 = (bid & 3) * 128, n0 = (bid >> 2) * 128;
        const int nsteps = (m0 < 256) ? 32 : 16;
        gemm_body<true>(m0, n0, 0, nsteps, wm, 1024, xT, aggT, topo, bvp,
                        uvT, sxe, nullptr, A, B);
    } else {
        const int e = bid - 256;
        const int m0 = (e & 1) * 128;
        const int g = e >> 1, kk = g % 6, n0 = (g / 6) * 128;
        gemm_body<false>(m0, n0, kk, 16, we2, 512, xT, aggT, topo, bvp,
                         nullptr, nullptr, se, A, B);
    }
}

// ---------------------------------------------------------------------------
// k_comb: ur = sum_k wr'_k * leaky(sxe + se_k + be'); updT = uvT * leaky(ur+br')
// sxe now bf16.
// ---------------------------------------------------------------------------
__global__ __launch_bounds__(256) void k_comb(
    const bf16* __restrict__ sxe, const bf16* __restrict__ se,
    const bf16* __restrict__ uvT, const float* __restrict__ bep,
    const float* __restrict__ P, bf16* __restrict__ updT)
{
    const int g = blockIdx.x * 256 + threadIdx.x;
    const int row = g >> 5, o0 = (g & 31) * 8;
    const size_t base = (size_t)row * C2 + o0;

    bf16x8 sx8 = *(const bf16x8*)(sxe + base);
    f32x4 be0 = *(const f32x4*)(bep + o0);
    f32x4 be1 = *(const f32x4*)(bep + o0 + 4);
    float sb[8];
    #pragma unroll
    for (int i = 0; i < 4; i++) {
        sb[i]     = (float)sx8[i]     + be0[i];
        sb[i + 4] = (float)sx8[i + 4] + be1[i];
    }
    float ur[8] = {};
    #pragma unroll
    for (int k = 0; k < 6; k++) {
        bf16x8 s8 = *(const bf16x8*)(se + (size_t)k * NROWS * C2 + base);
        const float wrk = P[8 + k];
        #pragma unroll
        for (int i = 0; i < 8; i++)
            ur[i] = fmaf(wrk, leaky(sb[i] + (float)s8[i]), ur[i]);
    }
    const float brp = P[14];
    bf16x8 uv8 = *(const bf16x8*)(uvT + base);
    bf16x8 o8;
    #pragma unroll
    for (int i = 0; i < 8; i++)
        o8[i] = (bf16)((float)uv8[i] * leaky(ur[i] + brp));
    *(bf16x8*)(updT + base) = o8;
}

// ---------------------------------------------------------------------------
// k_out: round-10/16 version (BK=64, swizzled gload_lds, XCD panel swizzle).
// ---------------------------------------------------------------------------
__global__ __launch_bounds__(256, 2) void k_out(
    const bf16* __restrict__ xT, const bf16* __restrict__ updT,
    const bf16* __restrict__ wf, const float* __restrict__ bfp,
    float* __restrict__ out)
{
    __shared__ __align__(16) bf16 A[2][128 * 64];
    __shared__ __align__(16) bf16 B[2][128 * 64];
    const int t = threadIdx.x, lane = t & 63;
    const int wv = t >> 6, wmi = wv >> 1, wni = wv & 1;
    const int lr = lane & 15, kg = lane >> 4;
    const int lb = (blockIdx.x & 7) * 32 + (blockIdx.x >> 3);
    const int n0 = (lb >> 2) * 128, m0 = (lb & 3) * 128;

    const bf16* wAb = wf   + (size_t)m0 * 768;
    const bf16* xTb = xT   + (size_t)n0 * C;
    const bf16* uTb = updT + (size_t)n0 * C2;

    f32x4 acc[4][4];
    #pragma unroll
    for (int mb = 0; mb < 4; mb++)
        #pragma unroll
        for (int nb = 0; nb < 4; nb++) acc[mb][nb] = 0.f;

    auto stageStep = [&](int buf, int s) {
        stage_gl64(A[buf], wAb, 768, s * 64, wv, lane);
        if (s < 8) stage_gl64(B[buf], xTb, C, s * 64, wv, lane);
        else       stage_gl64(B[buf], uTb, C2, (s - 8) * 64, wv, lane);
    };

    stageStep(0, 0);
    int cb = 0;
    #pragma unroll 1
    for (int s = 0; s < 12; ++s) {
        __syncthreads();
        if (s + 1 < 12) stageStep(cb ^ 1, s + 1);
        mmstep64(A[cb], B[cb], acc, wmi * 64, wni * 64, lr, kg);
        cb ^= 1;
    }

    #pragma unroll
    for (int mb = 0; mb < 4; mb++) {
        const int o = m0 + wmi * 64 + mb * 16 + kg * 4;
        f32x4 bf4 = *(const f32x4*)(bfp + o);
        #pragma unroll
        for (int nb = 0; nb < 4; nb++) {
            const int col = n0 + wni * 64 + nb * 16 + lr;
            const int b = col >> 12, v = col & 4095;
            #pragma unroll
            for (int q = 0; q < 4; q++)
                out[(((size_t)b * C + o + q) << 12) + v] = leaky(acc[mb][nb][q] + bf4[q]);
        }
    }
}

// ---------------------------------------------------------------------------
extern "C" void kernel_launch(void* const* d_in, const int* in_sizes, int n_in,
                              void* d_out, int out_size, void* d_ws, size_t ws_size,
                              hipStream_t stream)
{
    const float* x    = (const float*)d_in[0];
    const float* topo = (const float*)d_in[1];
    const float* w_ea = (const float*)d_in[2];
    const float* b_ea = (const float*)d_in[3];
    const float* g_ea = (const float*)d_in[4];
    const float* be_ea= (const float*)d_in[5];
    const float* rm_ea= (const float*)d_in[6];
    const float* rv_ea= (const float*)d_in[7];
    const float* w_v  = (const float*)d_in[8];
    const float* b_v  = (const float*)d_in[9];
    const float* g_v  = (const float*)d_in[10];
    const float* be_v = (const float*)d_in[11];
    const float* rm_v = (const float*)d_in[12];
    const float* rv_v = (const float*)d_in[13];
    const float* w_e  = (const float*)d_in[14];
    const float* b_e  = (const float*)d_in[15];
    const float* g_e  = (const float*)d_in[16];
    const float* be_e = (const float*)d_in[17];
    const float* rm_e = (const float*)d_in[18];
    const float* rv_e = (const float*)d_in[19];
    const float* w_r  = (const float*)d_in[20];
    const float* b_r  = (const float*)d_in[21];
    const float* g_r  = (const float*)d_in[22];
    const float* be_r = (const float*)d_in[23];
    const float* rm_r = (const float*)d_in[24];
    const float* rv_r = (const float*)d_in[25];
    const float* w_f  = (const float*)d_in[26];
    const float* g_f  = (const float*)d_in[27];
    const float* be_f = (const float*)d_in[28];
    const float* rm_f = (const float*)d_in[29];
    const float* rv_f = (const float*)d_in[30];

    char* base = (char*)d_ws;
    size_t off = 0;
    auto take = [&](size_t bytes) { size_t r = off; off = (off + bytes + 255) & ~(size_t)255; return r; };
    float* P    = (float*)(base + take(64 * 4));
    float* bvp  = (float*)(base + take(256 * 4));
    float* bep  = (float*)(base + take(256 * 4));
    float* bfp  = (float*)(base + take(512 * 4));
    bf16*  wmp  = (bf16*)(base + take((size_t)524288 * 2));
    bf16*  we2p = (bf16*)(base + take((size_t)131072 * 2));
    bf16*  wfp  = (bf16*)(base + take((size_t)393216 * 2));
    bf16*  xT   = (bf16*)(base + take((size_t)NROWS * C * 2));
    bf16*  aggT = (bf16*)(base + take((size_t)NROWS * C * 2));
    bf16*  uvT  = (bf16*)(base + take((size_t)NROWS * C2 * 2));
    bf16*  updT = (bf16*)(base + take((size_t)NROWS * C2 * 2));
    bf16*  sxe  = (bf16*)(base + take((size_t)NROWS * C2 * 2));
    bf16*  se   = (bf16*)(base + take((size_t)6 * NROWS * C2 * 2));

    k_pa<<<dim3(5120), 256, 0, stream>>>(
        x, topo, w_v, w_e, w_f,
        w_ea, b_ea, g_ea, be_ea, rm_ea, rv_ea,
        b_v, g_v, be_v, rm_v, rv_v,
        b_e, g_e, be_e, rm_e, rv_e,
        w_r, b_r, g_r, be_r, rm_r, rv_r,
        g_f, be_f, rm_f, rv_f,
        P, bvp, bep, bfp, wmp, we2p, wfp, xT, aggT);

    k_gemm<<<dim3(1024), 256, 0, stream>>>(xT, aggT, wmp, we2p, bvp, topo, uvT, sxe, se);
    k_comb<<<dim3(NROWS * C2 / 8 / 256), 256, 0, stream>>>(sxe, se, uvT, bep, P, updT);
    k_out<<<dim3(256), 256, 0, stream>>>(xT, updT, wfp, bfp, (float*)d_out);
}